// Round 13
// baseline (174.517 us; speedup 1.0000x reference)
//
#include <hip/hip_runtime.h>

typedef unsigned short ushort_t;
typedef __attribute__((ext_vector_type(8))) short short8;
typedef __attribute__((ext_vector_type(8))) _Float16 half8;
typedef __attribute__((ext_vector_type(4))) float f32x4;
typedef __attribute__((ext_vector_type(16))) float f32x16;
typedef __attribute__((ext_vector_type(2))) unsigned uint2v;
typedef __attribute__((ext_vector_type(4))) unsigned uint4v;

#define LOG2E 1.44269504088896f

// async global->LDS, 16B per lane. LDS dest must be wave-uniform base + lane*16.
__device__ __forceinline__ void async16(const void* g, void* l) {
  __builtin_amdgcn_global_load_lds(
      (const __attribute__((address_space(1))) void*)g,
      (__attribute__((address_space(3))) void*)l, 16, 0, 0);
}

__device__ __forceinline__ ushort_t f2h(float f) {
  union { _Float16 h; ushort_t u; } c; c.h = (_Float16)f; return c.u;
}

__device__ __forceinline__ half8 u4h8(uint4v u) { union { uint4v a; half8 b; } c; c.a = u; return c.b; }

__device__ __forceinline__ f32x16 zero16() {
  f32x16 v;
  #pragma unroll
  for (int i = 0; i < 16; i++) v[i] = 0.f;
  return v;
}

// ------------- merged ingest: weight transpose AND activation cast, fp16 ----
// (round-8 exact)
__global__ __launch_bounds__(256) void prep_all(const float* __restrict__ cur,
                                                const float* __restrict__ hid,
                                                const float* __restrict__ Wq,
                                                const float* __restrict__ Wkv,
                                                const float* __restrict__ Wo,
                                                ushort_t* __restrict__ ch,
                                                ushort_t* __restrict__ hh,
                                                ushort_t* __restrict__ qT,
                                                ushort_t* __restrict__ kvT,
                                                ushort_t* __restrict__ oT) {
  __shared__ float tile[32][33];
  int bid = blockIdx.x;
  if (bid >= 1024) {
    int i = (bid - 1024) * 256 + threadIdx.x;       // 0 .. 2*524288-1
    const float* src;
    ushort_t* dst;
    int j;
    if (i < 524288) { src = cur; dst = ch; j = i; }
    else            { src = hid; dst = hh; j = i - 524288; }
    const f32x4* s = (const f32x4*)src;
    f32x4 a = s[j * 2], b = s[j * 2 + 1];
    short8 o;
    #pragma unroll
    for (int k = 0; k < 4; k++) {
      o[k] = (short)f2h(a[k]);
      o[k + 4] = (short)f2h(b[k]);
    }
    ((short8*)dst)[j] = o;
    return;
  }
  const float* src; ushort_t* dh; int Nn, bx, by;
  const int K = 512;
  if (bid < 256)      { src = Wq;  dh = qT;  Nn = 512;  bx = (bid & 15) * 32; by = (bid >> 4) * 32; }
  else if (bid < 768) { int b = bid - 256; src = Wkv; dh = kvT; Nn = 1024; bx = (b & 31) * 32; by = (b >> 5) * 32; }
  else                { int b = bid - 768; src = Wo;  dh = oT;  Nn = 512;  bx = (b & 15) * 32; by = (b >> 4) * 32; }
  int tx = threadIdx.x & 31, ty = threadIdx.x >> 5;   // (32, 8)
  #pragma unroll
  for (int i = 0; i < 32; i += 8)
    tile[ty + i][tx] = src[(size_t)(by + ty + i) * Nn + bx + tx];
  __syncthreads();
  #pragma unroll
  for (int i = 0; i < 32; i += 8) {
    float v = tile[tx][ty + i];
    size_t idx = (size_t)(bx + ty + i) * K + by + tx;
    dh[idx] = f2h(v);
  }
}

// ---------------- merged q+kv projection: 256x256 tile, BK=64, 8 waves ----
// 192 blocks (kv: 32x4 = 128; q: 32x2 = 64) -> single residency round at
// 1 block/CU (128 KB LDS). 2-phase schedule (m230: 682 TF at this geometry):
//   stage(t+1) -> vmcnt(8) [t landed, t+1 in flight] -> barrier ->
//   compute(t) -> lgkmcnt(0) -> barrier.
// Swizzle: rows are 64 halves (128 B); source chunk ch ^= row&7, read chunk
// (ks*4+lq) ^ (row&7) -> 16-lane frag groups cover all 8 chunk slots exactly
// twice = 2-way = free. LDS dest linear for global_load_lds.
__global__ __launch_bounds__(512) void gemm_qkv(const ushort_t* __restrict__ H,
                                                const ushort_t* __restrict__ WkvT,
                                                ushort_t* __restrict__ ko,
                                                ushort_t* __restrict__ vt,
                                                const ushort_t* __restrict__ C,
                                                const ushort_t* __restrict__ WqT,
                                                ushort_t* __restrict__ qo) {
  __shared__ __align__(16) ushort_t Ash[2][16384];   // 2 x 32 KB
  __shared__ __align__(16) ushort_t Bsh[2][16384];   // 2 x 32 KB
  const int tid = threadIdx.x;
  const int wave = tid >> 6, lane = tid & 63;
  const int wm = (wave >> 2) * 128, wn = (wave & 3) * 64;   // 2x4 wave grid
  const int lrow = lane & 15, lq = lane >> 4;
  const int K = 512;

  int bid = blockIdx.x;
  int w = (bid & 7) * 24 + (bid >> 3);      // 192 = 8*24, XCD-bijective
  const ushort_t *A, *B;
  int m0, n0, epi;
  if (w < 128) { A = H; B = WkvT; m0 = (w >> 2) * 256; n0 = (w & 3) * 256; epi = 1; }
  else { int ww = w - 128; A = C; B = WqT; m0 = (ww >> 1) * 256; n0 = (ww & 1) * 256; epi = 0; }

  f32x4 acc[8][4];
  const f32x4 z = {0.f, 0.f, 0.f, 0.f};
  #pragma unroll
  for (int i = 0; i < 8; i++)
    #pragma unroll
    for (int j = 0; j < 4; j++) acc[i][j] = z;

  auto stage = [&](int t, int d) {
    const int k0 = t * 64;
    #pragma unroll
    for (int i = 0; i < 4; i++) {            // A tile: 256 rows x 8 chunks
      int g = i * 512 + tid, r = g >> 3, chs = (g & 7) ^ (r & 7);
      async16(&A[(size_t)(m0 + r) * K + k0 + chs * 8], &Ash[d][g * 8]);
    }
    #pragma unroll
    for (int i = 0; i < 4; i++) {            // B tile: 256 rows x 8 chunks
      int g = i * 512 + tid, r = g >> 3, chs = (g & 7) ^ (r & 7);
      async16(&B[(size_t)(n0 + r) * K + k0 + chs * 8], &Bsh[d][g * 8]);
    }
  };

  stage(0, 0);
  for (int t = 0; t < 8; t++) {              // 8 K-steps of 64
    if (t < 7) {
      stage(t + 1, (t + 1) & 1);             // 8 loads/thread stay in flight
      asm volatile("s_waitcnt vmcnt(8)" ::: "memory");   // tile t landed
    } else {
      asm volatile("s_waitcnt vmcnt(0)" ::: "memory");
    }
    __builtin_amdgcn_s_barrier();

    const int d = t & 1;
    #pragma unroll
    for (int ks = 0; ks < 2; ks++) {
      half8 af[8], bf[4];
      #pragma unroll
      for (int ti = 0; ti < 8; ti++) {
        int row = wm + ti * 16 + lrow;
        af[ti] = *(const half8*)&Ash[d][row * 64 + ((ks * 4 + lq) ^ (row & 7)) * 8];
      }
      #pragma unroll
      for (int tj = 0; tj < 4; tj++) {
        int row = wn + tj * 16 + lrow;
        bf[tj] = *(const half8*)&Bsh[d][row * 64 + ((ks * 4 + lq) ^ (row & 7)) * 8];
      }
      #pragma unroll
      for (int ti = 0; ti < 8; ti++)
        #pragma unroll
        for (int tj = 0; tj < 4; tj++)
          acc[ti][tj] = __builtin_amdgcn_mfma_f32_16x16x32_f16(af[ti], bf[tj], acc[ti][tj], 0, 0, 0);
    }

    if (t < 7) {   // all readers done before a later stage overwrites this buf
      asm volatile("s_waitcnt lgkmcnt(0)" ::: "memory");
      __builtin_amdgcn_s_barrier();
    }
  }

  // epilogue
  #pragma unroll
  for (int ti = 0; ti < 8; ti++) {
    #pragma unroll
    for (int tj = 0; tj < 4; tj++) {
      int row0 = m0 + wm + ti * 16 + lq * 4;
      int col = n0 + wn + tj * 16 + lrow;
      #pragma unroll
      for (int r = 0; r < 4; r++) {
        int m = row0 + r;
        float fv = acc[ti][tj][r];
        if (epi == 0) {
          // q-layout [B*H][N][D]
          size_t idx = (size_t)((m >> 10) * 8 + (col >> 6)) * 65536 + (m & 1023) * 64 + (col & 63);
          qo[idx] = f2h(fv);
        } else {
          if (col < 512) {   // k-layout
            size_t idx = (size_t)((m >> 10) * 8 + (col >> 6)) * 65536 + (m & 1023) * 64 + (col & 63);
            ko[idx] = f2h(fv);
          } else {           // v^T layout [B*H][D][N]
            int cc = col - 512;
            vt[(size_t)(((m >> 10) * 8 + (cc >> 6)) * 64 + (cc & 63)) * 1024 + (m & 1023)] = f2h(fv);
          }
        }
      }
    }
  }
}

// ---- fp16 GEMM body (round-8 exact): triple-buffered LDS, depth-2 prefetch ----
__device__ __forceinline__ void gemm_o_body(const ushort_t* __restrict__ A,
                                            const ushort_t* __restrict__ B,
                                            float* __restrict__ outf,
                                            int K, int ldo, int m0, int n0,
                                            ushort_t* lds) {
  constexpr int MT = 2, TN = 4;
  constexpr int ASZ = 64 * 32;
  constexpr int BSZ = 128 * 32;
  ushort_t* Ash = lds;               // [3][ASZ]
  ushort_t* Bsh = lds + 3 * ASZ;     // [3][BSZ]
  const int tid = threadIdx.x;
  const int wave = tid >> 6, lane = tid & 63;
  const int wm = (wave >> 1) * 32, wn = (wave & 1) * 64;
  const int lrow = lane & 15, lq = lane >> 4;

  f32x4 acc[MT][TN];
  const f32x4 z = {0.f, 0.f, 0.f, 0.f};
  #pragma unroll
  for (int i = 0; i < MT; i++)
    #pragma unroll
    for (int j = 0; j < TN; j++) acc[i][j] = z;

  auto stage = [&](int t, int d) {
    const int k0 = t * 32;
    {
      int r = tid >> 2, kc = tid & 3;
      int kcs = kc ^ ((r >> 1) & 3);
      async16(&A[(size_t)(m0 + r) * K + k0 + kcs * 8], &Ash[d * ASZ + tid * 8]);
    }
    #pragma unroll
    for (int i = 0; i < 2; i++) {
      int g = i * 256 + tid;
      int r = g >> 2, kc = g & 3;
      int kcs = kc ^ ((r >> 1) & 3);
      async16(&B[(size_t)(n0 + r) * K + k0 + kcs * 8], &Bsh[d * BSZ + g * 8]);
    }
  };

  const int nt = K >> 5;
  stage(0, 0);
  stage(1, 1);
  for (int t = 0; t < nt; t++) {
    if (t + 2 < nt) stage(t + 2, (t + 2) % 3);
    if (t + 2 < nt)      asm volatile("s_waitcnt vmcnt(6)" ::: "memory");
    else if (t + 1 < nt) asm volatile("s_waitcnt vmcnt(3)" ::: "memory");
    else                 asm volatile("s_waitcnt vmcnt(0)" ::: "memory");
    __builtin_amdgcn_s_barrier();

    const int d = t % 3;
    const int ab = d * ASZ, bb = d * BSZ;
    half8 af[MT], bf[TN];
    #pragma unroll
    for (int ti = 0; ti < MT; ti++) {
      int row = wm + ti * 16 + lrow;
      af[ti] = *(const half8*)&Ash[ab + row * 32 + (lq ^ ((row >> 1) & 3)) * 8];
    }
    #pragma unroll
    for (int tj = 0; tj < TN; tj++) {
      int row = wn + tj * 16 + lrow;
      bf[tj] = *(const half8*)&Bsh[bb + row * 32 + (lq ^ ((row >> 1) & 3)) * 8];
    }
    #pragma unroll
    for (int ti = 0; ti < MT; ti++)
      #pragma unroll
      for (int tj = 0; tj < TN; tj++)
        acc[ti][tj] = __builtin_amdgcn_mfma_f32_16x16x32_f16(af[ti], bf[tj], acc[ti][tj], 0, 0, 0);

    if (t + 1 < nt) {
      asm volatile("s_waitcnt lgkmcnt(0)" ::: "memory");
      __builtin_amdgcn_s_barrier();
    }
  }

  #pragma unroll
  for (int ti = 0; ti < MT; ti++) {
    #pragma unroll
    for (int tj = 0; tj < TN; tj++) {
      int row0 = m0 + wm + ti * 16 + lq * 4;
      int col = n0 + wn + tj * 16 + lrow;
      #pragma unroll
      for (int r = 0; r < 4; r++)
        outf[(size_t)(row0 + r) * ldo + col] = acc[ti][tj][r];
    }
  }
}

// output projection: 512 blocks (64x128 tiles), XCD remap, fp32 out.
__global__ __launch_bounds__(256) void gemm_o(const ushort_t* __restrict__ A,
                                              const ushort_t* __restrict__ B,
                                              float* __restrict__ outf) {
  __shared__ __align__(16) ushort_t lds[18432];   // 36 KB
  int bid = blockIdx.x;
  int w = (bid & 7) * 64 + (bid >> 3);
  int n0 = (w & 3) * 128, m0 = (w >> 2) * 64;
  gemm_o_body(A, B, outf, 512, 512, m0, n0, lds);
}

// ---------------- flash attention: round-8 exact + T13 defer-rescale ----------
__global__ __launch_bounds__(256, 2) void flash_attn(const ushort_t* __restrict__ qb,
                                                     const ushort_t* __restrict__ kb,
                                                     const ushort_t* __restrict__ vtb,
                                                     ushort_t* __restrict__ ob) {
  __shared__ __align__(16) ushort_t Ksh[2][64 * 64];
  __shared__ __align__(16) ushort_t VTs[2][64 * 64];

  const int tid = threadIdx.x;
  const int wave = tid >> 6, lane = tid & 63;
  const int bh = blockIdx.x & 63, qt = blockIdx.x >> 6;
  const int l31 = lane & 31, hi = lane >> 5;

  const ushort_t* Q = qb + (size_t)bh * 65536;
  const ushort_t* Kp = kb + (size_t)bh * 65536;
  const ushort_t* VT = vtb + (size_t)bh * 65536;

  const int qrow0 = qt * 128 + wave * 32;

  half8 qf[4];
  #pragma unroll
  for (int ds = 0; ds < 4; ds++)
    qf[ds] = *(const half8*)&Q[(size_t)(qrow0 + l31) * 64 + ds * 16 + hi * 8];

  f32x16 oacc[2];
  oacc[0] = zero16();
  oacc[1] = zero16();
  float m_i = -1e30f, l_i = 0.f;

  const int r7 = l31 & 7;
  int pc[4];
  #pragma unroll
  for (int i = 0; i < 4; i++) pc[i] = (((2 * i + hi) ^ r7) << 3);
  const int ro0 = l31 * 64, ro1 = ro0 + 2048;

  auto stage = [&](int kt, int d) {
    #pragma unroll
    for (int i = 0; i < 2; i++) {
      int g = i * 256 + tid, rw = g >> 3, ch = g & 7;
      int co = ((ch ^ (rw & 7)) << 3);
      int lofs = rw * 64 + (ch << 3);
      async16(&Kp[(size_t)(kt * 64 + rw) * 64 + co], &Ksh[d][lofs]);
      async16(&VT[(size_t)rw * 1024 + kt * 64 + co], &VTs[d][lofs]);
    }
  };

  stage(0, 0);

  for (int kt = 0; kt < 16; kt++) {
    const int cur = kt & 1;
    if (kt < 15) {
      stage(kt + 1, cur ^ 1);
      asm volatile("s_waitcnt vmcnt(4)" ::: "memory");
    } else {
      asm volatile("s_waitcnt vmcnt(0)" ::: "memory");
    }
    __builtin_amdgcn_s_barrier();

    f32x16 sacc0 = zero16(), sacc1 = zero16();
    __builtin_amdgcn_s_setprio(1);
    #pragma unroll
    for (int ds = 0; ds < 4; ds++) {
      half8 k0 = *(const half8*)&Ksh[cur][ro0 + pc[ds]];
      half8 k1 = *(const half8*)&Ksh[cur][ro1 + pc[ds]];
      sacc0 = __builtin_amdgcn_mfma_f32_32x32x16_f16(k0, qf[ds], sacc0, 0, 0, 0);
      sacc1 = __builtin_amdgcn_mfma_f32_32x32x16_f16(k1, qf[ds], sacc1, 0, 0, 0);
    }
    __builtin_amdgcn_s_setprio(0);

    float mx = -1e30f;
    #pragma unroll
    for (int r = 0; r < 16; r++) {
      mx = fmaxf(mx, sacc0[r]);
      mx = fmaxf(mx, sacc1[r]);
    }
    mx = fmaxf(mx, __shfl_xor(mx, 32));

    // T13 defer-rescale: skip O/l rescale while the running max still covers
    // this tile within 8 bits of headroom (P <= 2^8, fp16-safe). Wave-uniform.
    if (!__all(mx <= m_i + 5.5451774f)) {   // 8 / log2(e)
      float mnew = fmaxf(m_i, mx);
      float alpha = exp2f((m_i - mnew) * LOG2E);
      l_i *= alpha;
      #pragma unroll
      for (int r = 0; r < 16; r++) {
        oacc[0][r] *= alpha;
        oacc[1][r] *= alpha;
      }
      m_i = mnew;
    }
    float mL = m_i * LOG2E;

    float sum = 0.f;
    unsigned pw[16];
    #pragma unroll
    for (int j = 0; j < 8; j++) {
      float p0 = exp2f(fmaf(sacc0[2 * j], LOG2E, -mL));
      float p1 = exp2f(fmaf(sacc0[2 * j + 1], LOG2E, -mL));
      sum += p0 + p1;
      asm("v_cvt_pkrtz_f16_f32 %0, %1, %2" : "=v"(pw[j]) : "v"(p0), "v"(p1));
    }
    #pragma unroll
    for (int j = 0; j < 8; j++) {
      float p0 = exp2f(fmaf(sacc1[2 * j], LOG2E, -mL));
      float p1 = exp2f(fmaf(sacc1[2 * j + 1], LOG2E, -mL));
      sum += p0 + p1;
      asm("v_cvt_pkrtz_f16_f32 %0, %1, %2" : "=v"(pw[8 + j]) : "v"(p0), "v"(p1));
    }
    sum += __shfl_xor(sum, 32);
    l_i += sum;

    __builtin_amdgcn_s_setprio(1);
    #pragma unroll
    for (int ks = 0; ks < 4; ks++) {
      const int base = (ks >> 1) * 8 + (ks & 1) * 4;
      uint2v s0 = __builtin_amdgcn_permlane32_swap(pw[base + 0], pw[base + 2], false, false);
      uint2v s1 = __builtin_amdgcn_permlane32_swap(pw[base + 1], pw[base + 3], false, false);
      half8 pfrag = u4h8((uint4v){s0.x, s1.x, s0.y, s1.y});
      half8 vf0 = *(const half8*)&VTs[cur][ro0 + pc[ks]];
      half8 vf1 = *(const half8*)&VTs[cur][ro1 + pc[ks]];
      oacc[0] = __builtin_amdgcn_mfma_f32_32x32x16_f16(vf0, pfrag, oacc[0], 0, 0, 0);
      oacc[1] = __builtin_amdgcn_mfma_f32_32x32x16_f16(vf1, pfrag, oacc[1], 0, 0, 0);
    }
    __builtin_amdgcn_s_setprio(0);

    if (kt < 15) {
      asm volatile("s_waitcnt lgkmcnt(0)" ::: "memory");
      __builtin_amdgcn_s_barrier();
    }
  }

  const int b = bh >> 3, h = bh & 7;
  const int n = qrow0 + l31;
  float rinv = 1.f / l_i;
  #pragma unroll
  for (int dt = 0; dt < 2; dt++) {
    #pragma unroll
    for (int t = 0; t < 4; t++) {
      ushort_t hv[4];
      #pragma unroll
      for (int e = 0; e < 4; e++)
        hv[e] = f2h(oacc[dt][4 * t + e] * rinv);
      size_t idx = (size_t)(b * 1024 + n) * 512 + h * 64 + dt * 32 + t * 8 + hi * 4;
      *(uint2v*)&ob[idx] = (uint2v){(unsigned)hv[0] | ((unsigned)hv[1] << 16),
                                    (unsigned)hv[2] | ((unsigned)hv[3] << 16)};
    }
  }
}

// ---------------- launcher ----------------
extern "C" void kernel_launch(void* const* d_in, const int* in_sizes, int n_in,
                              void* d_out, int out_size, void* d_ws, size_t ws_size,
                              hipStream_t stream) {
  const float* cur = (const float*)d_in[0];   // [8,1024,512] fp32
  const float* hid = (const float*)d_in[1];   // [8,1024,512] fp32
  const float* Wq  = (const float*)d_in[2];   // [512,512]
  const float* Wkv = (const float*)d_in[3];   // [512,1024]
  const float* Wo  = (const float*)d_in[4];   // [512,512]

  ushort_t* ws = (ushort_t*)d_ws;
  ushort_t* C   = ws;                   // 4,194,304  (cur fp16; reused: attn out)
  ushort_t* H   = C + 4194304;          // 4,194,304  (hid fp16)
  ushort_t* ko  = H + 4194304;          // 4,194,304  (k, k-layout)
  ushort_t* vt  = ko + 4194304;         // 4,194,304  (v^T layout)
  ushort_t* qo  = vt + 4194304;         // 4,194,304  (q, q-layout)
  ushort_t* WqT = qo + 4194304;         // 262,144
  ushort_t* WkvT = WqT + 262144;        // 524,288
  ushort_t* WoT = WkvT + 524288;        // 262,144

  // merged ingest: weight transpose (blocks 0..1023) + activation cast (1024..5119)
  prep_all<<<5120, 256, 0, stream>>>(cur, hid, Wq, Wkv, Wo, C, H, WqT, WkvT, WoT);

  // merged kv + q projections: 192 blocks, 256x256 tiles, 512 threads
  gemm_qkv<<<192, 512, 0, stream>>>(H, WkvT, ko, vt, C, WqT, qo);

  // attention: 512 blocks (head-major XCD grouping), 128 q-rows/block; out -> C
  flash_attn<<<512, 256, 0, stream>>>(qo, ko, vt, C);

  // output projection: 512 blocks -> fp32 d_out
  gemm_o<<<512, 256, 0, stream>>>(C, WoT, (float*)d_out);
}

// Round 14
// 166.885 us; speedup vs baseline: 1.0457x; 1.0457x over previous
//
#include <hip/hip_runtime.h>

typedef unsigned short ushort_t;
typedef __attribute__((ext_vector_type(8))) short short8;
typedef __attribute__((ext_vector_type(8))) _Float16 half8;
typedef __attribute__((ext_vector_type(4))) float f32x4;
typedef __attribute__((ext_vector_type(16))) float f32x16;
typedef __attribute__((ext_vector_type(2))) unsigned uint2v;
typedef __attribute__((ext_vector_type(4))) unsigned uint4v;

#define LOG2E 1.44269504088896f

// async global->LDS, 16B per lane. LDS dest must be wave-uniform base + lane*16.
__device__ __forceinline__ void async16(const void* g, void* l) {
  __builtin_amdgcn_global_load_lds(
      (const __attribute__((address_space(1))) void*)g,
      (__attribute__((address_space(3))) void*)l, 16, 0, 0);
}

__device__ __forceinline__ ushort_t f2h(float f) {
  union { _Float16 h; ushort_t u; } c; c.h = (_Float16)f; return c.u;
}

__device__ __forceinline__ half8 u4h8(uint4v u) { union { uint4v a; half8 b; } c; c.a = u; return c.b; }

__device__ __forceinline__ f32x16 zero16() {
  f32x16 v;
  #pragma unroll
  for (int i = 0; i < 16; i++) v[i] = 0.f;
  return v;
}

// ------------- merged ingest: weight transpose AND activation cast, fp16 ----
// blocks 0..1023: transpose Wq/Wkv/Wo -> fp16 [N][K] (B^T layout)
// blocks 1024..5119: cast cur/hid fp32 -> fp16
__global__ __launch_bounds__(256) void prep_all(const float* __restrict__ cur,
                                                const float* __restrict__ hid,
                                                const float* __restrict__ Wq,
                                                const float* __restrict__ Wkv,
                                                const float* __restrict__ Wo,
                                                ushort_t* __restrict__ ch,
                                                ushort_t* __restrict__ hh,
                                                ushort_t* __restrict__ qT,
                                                ushort_t* __restrict__ kvT,
                                                ushort_t* __restrict__ oT) {
  __shared__ float tile[32][33];
  int bid = blockIdx.x;
  if (bid >= 1024) {
    // ---- activation cast path ----
    int i = (bid - 1024) * 256 + threadIdx.x;       // 0 .. 2*524288-1
    const float* src;
    ushort_t* dst;
    int j;
    if (i < 524288) { src = cur; dst = ch; j = i; }
    else            { src = hid; dst = hh; j = i - 524288; }
    const f32x4* s = (const f32x4*)src;
    f32x4 a = s[j * 2], b = s[j * 2 + 1];
    short8 o;
    #pragma unroll
    for (int k = 0; k < 4; k++) {
      o[k] = (short)f2h(a[k]);
      o[k + 4] = (short)f2h(b[k]);
    }
    ((short8*)dst)[j] = o;
    return;
  }
  // ---- weight transpose path ----
  const float* src; ushort_t* dh; int Nn, bx, by;
  const int K = 512;
  if (bid < 256)      { src = Wq;  dh = qT;  Nn = 512;  bx = (bid & 15) * 32; by = (bid >> 4) * 32; }
  else if (bid < 768) { int b = bid - 256; src = Wkv; dh = kvT; Nn = 1024; bx = (b & 31) * 32; by = (b >> 5) * 32; }
  else                { int b = bid - 768; src = Wo;  dh = oT;  Nn = 512;  bx = (b & 15) * 32; by = (b >> 4) * 32; }
  int tx = threadIdx.x & 31, ty = threadIdx.x >> 5;   // (32, 8)
  #pragma unroll
  for (int i = 0; i < 32; i += 8)
    tile[ty + i][tx] = src[(size_t)(by + ty + i) * Nn + bx + tx];
  __syncthreads();
  #pragma unroll
  for (int i = 0; i < 32; i += 8) {
    float v = tile[tx][ty + i];
    size_t idx = (size_t)(bx + ty + i) * K + by + tx;
    dh[idx] = f2h(v);
  }
}

// ---- fp16 GEMM body: C = A[M][K] @ B[Nn][K]^T, fp32 accumulate ----
// Wave tile (MT*16)x(TN*16); block (MT*32)x(TN*32); 4 waves (2x2).
// Triple-buffered LDS, depth-2 prefetch (T3/T4):
//   stage(t+2) -> vmcnt(2*LPS) [t landed; t+1,t+2 in flight] -> barrier ->
//   compute(t) -> lgkmcnt(0) -> barrier.
// T2 swizzle both-sides (0-conflict verified r6): source chunk kc ^= (row>>1)&3,
// read chunk lq ^= (row>>1)&3; LDS dest stays linear for global_load_lds.
template<int EPI, int MT, int TN>
__device__ __forceinline__ void gemm_body(const ushort_t* __restrict__ A,
                                          const ushort_t* __restrict__ B,
                                          ushort_t* __restrict__ o_16,
                                          ushort_t* __restrict__ o_vt,
                                          float* __restrict__ outf,
                                          int K, int ldo, int m0, int n0,
                                          ushort_t* lds) {
  constexpr int BM = MT * 32;
  constexpr int BN = TN * 32;
  constexpr int ASZ = BM * 32;       // halves per A buffer
  constexpr int BSZ = BN * 32;       // halves per B buffer
  constexpr int LPS = (MT + TN) / 2; // async16 per thread per stage
  ushort_t* Ash = lds;               // [3][ASZ]
  ushort_t* Bsh = lds + 3 * ASZ;     // [3][BSZ]
  const int tid = threadIdx.x;
  const int wave = tid >> 6, lane = tid & 63;
  const int wm = (wave >> 1) * (MT * 16), wn = (wave & 1) * (TN * 16);
  const int lrow = lane & 15, lq = lane >> 4;

  f32x4 acc[MT][TN];
  const f32x4 z = {0.f, 0.f, 0.f, 0.f};
  #pragma unroll
  for (int i = 0; i < MT; i++)
    #pragma unroll
    for (int j = 0; j < TN; j++) acc[i][j] = z;

  auto stage = [&](int t, int d) {
    const int k0 = t * 32;
    const int aoff = d * ASZ, boff = d * BSZ;
    #pragma unroll
    for (int i = 0; i < MT / 2; i++) {       // A tile: BM rows x 4 chunks
      int g = i * 256 + tid;
      int r = g >> 2, kc = g & 3;
      int kcs = kc ^ ((r >> 1) & 3);         // pre-swizzled source chunk
      async16(&A[(size_t)(m0 + r) * K + k0 + kcs * 8], &Ash[aoff + g * 8]);
    }
    #pragma unroll
    for (int i = 0; i < TN / 2; i++) {       // B tile: BN rows x 4 chunks
      int g = i * 256 + tid;
      int r = g >> 2, kc = g & 3;
      int kcs = kc ^ ((r >> 1) & 3);
      async16(&B[(size_t)(n0 + r) * K + k0 + kcs * 8], &Bsh[boff + g * 8]);
    }
  };

  const int nt = K >> 5;                     // 16 K-tiles
  stage(0, 0);
  stage(1, 1);
  for (int t = 0; t < nt; t++) {
    if (t + 2 < nt) stage(t + 2, (t + 2) % 3);
    // wait: stage(t) landed; up to 2 stages (2*LPS loads) stay in flight
    if (t + 2 < nt) {
      if constexpr (LPS == 4) asm volatile("s_waitcnt vmcnt(8)" ::: "memory");
      else                    asm volatile("s_waitcnt vmcnt(6)" ::: "memory");
    } else if (t + 1 < nt) {
      if constexpr (LPS == 4) asm volatile("s_waitcnt vmcnt(4)" ::: "memory");
      else                    asm volatile("s_waitcnt vmcnt(3)" ::: "memory");
    } else {
      asm volatile("s_waitcnt vmcnt(0)" ::: "memory");
    }
    __builtin_amdgcn_s_barrier();

    const int d = t % 3;
    const int ab = d * ASZ, bb = d * BSZ;
    half8 af[MT], bf[TN];
    #pragma unroll
    for (int ti = 0; ti < MT; ti++) {
      int row = wm + ti * 16 + lrow;
      af[ti] = *(const half8*)&Ash[ab + row * 32 + (lq ^ ((row >> 1) & 3)) * 8];
    }
    #pragma unroll
    for (int tj = 0; tj < TN; tj++) {
      int row = wn + tj * 16 + lrow;
      bf[tj] = *(const half8*)&Bsh[bb + row * 32 + (lq ^ ((row >> 1) & 3)) * 8];
    }
    #pragma unroll
    for (int ti = 0; ti < MT; ti++)
      #pragma unroll
      for (int tj = 0; tj < TN; tj++)
        acc[ti][tj] = __builtin_amdgcn_mfma_f32_16x16x32_f16(af[ti], bf[tj], acc[ti][tj], 0, 0, 0);

    if (t + 1 < nt) {   // readers done before a later stage overwrites this buf
      asm volatile("s_waitcnt lgkmcnt(0)" ::: "memory");
      __builtin_amdgcn_s_barrier();
    }
  }

  // epilogue
  #pragma unroll
  for (int ti = 0; ti < MT; ti++) {
    #pragma unroll
    for (int tj = 0; tj < TN; tj++) {
      int row0 = m0 + wm + ti * 16 + lq * 4;
      int col = n0 + wn + tj * 16 + lrow;
      #pragma unroll
      for (int r = 0; r < 4; r++) {
        int m = row0 + r;
        float fv = acc[ti][tj][r];
        if (EPI == 0) {
          // q-layout [B*H][N][D]
          size_t idx = (size_t)((m >> 10) * 8 + (col >> 6)) * 65536 + (m & 1023) * 64 + (col & 63);
          o_16[idx] = f2h(fv);
        } else if (EPI == 1) {
          if (col < 512) {   // k-layout
            size_t idx = (size_t)((m >> 10) * 8 + (col >> 6)) * 65536 + (m & 1023) * 64 + (col & 63);
            o_16[idx] = f2h(fv);
          } else {           // v^T layout [B*H][D][N]
            int cc = col - 512;
            o_vt[(size_t)(((m >> 10) * 8 + (cc >> 6)) * 64 + (cc & 63)) * 1024 + (m & 1023)] = f2h(fv);
          }
        } else {
          outf[(size_t)m * ldo + col] = fv;   // fp32 final output
        }
      }
    }
  }
}

// merged q+kv projection: 768 blocks (128x128 tiles), XCD remap (768 = 8*96).
// w < 512 -> kv (grid 8x64), w >= 512 -> q (grid 4x64). Block-uniform branch.
__global__ __launch_bounds__(256) void gemm_qkv(const ushort_t* __restrict__ H,
                                                const ushort_t* __restrict__ WkvT,
                                                ushort_t* __restrict__ ko,
                                                ushort_t* __restrict__ vt,
                                                const ushort_t* __restrict__ C,
                                                const ushort_t* __restrict__ WqT,
                                                ushort_t* __restrict__ qo) {
  __shared__ __align__(16) ushort_t lds[24576];   // 48 KB: 3 x (8KB A + 8KB B)
  int bid = blockIdx.x;
  int w = (bid & 7) * 96 + (bid >> 3);       // contiguous work per XCD
  if (w < 512) {
    int n0 = (w & 7) * 128, m0 = (w >> 3) * 128;
    gemm_body<1, 4, 4>(H, WkvT, ko, vt, (float*)nullptr, 512, 0, m0, n0, lds);
  } else {
    int ww = w - 512;
    int n0 = (ww & 3) * 128, m0 = (ww >> 2) * 128;
    gemm_body<0, 4, 4>(C, WqT, qo, (ushort_t*)nullptr, (float*)nullptr, 512, 0, m0, n0, lds);
  }
}

// output projection: 512 blocks (64x128 tiles), XCD remap (512 = 8*64), fp32 out.
__global__ __launch_bounds__(256) void gemm_o(const ushort_t* __restrict__ A,
                                              const ushort_t* __restrict__ B,
                                              float* __restrict__ outf) {
  __shared__ __align__(16) ushort_t lds[18432];   // 36 KB: 3 x (4KB A + 8KB B)
  int bid = blockIdx.x;
  int w = (bid & 7) * 64 + (bid >> 3);
  int n0 = (w & 3) * 128, m0 = (w >> 2) * 64;
  gemm_body<2, 2, 4>(A, B, (ushort_t*)nullptr, (ushort_t*)nullptr, outf, 512, 512, m0, n0, lds);
}

// ---------------- flash attention: fp16, 32x32 core, counted-vmcnt ----------
// (round-8 exact: best measured configuration)
__global__ __launch_bounds__(256, 2) void flash_attn(const ushort_t* __restrict__ qb,
                                                     const ushort_t* __restrict__ kb,
                                                     const ushort_t* __restrict__ vtb,
                                                     ushort_t* __restrict__ ob) {
  __shared__ __align__(16) ushort_t Ksh[2][64 * 64];
  __shared__ __align__(16) ushort_t VTs[2][64 * 64];

  const int tid = threadIdx.x;
  const int wave = tid >> 6, lane = tid & 63;
  const int bh = blockIdx.x & 63, qt = blockIdx.x >> 6;
  const int l31 = lane & 31, hi = lane >> 5;

  const ushort_t* Q = qb + (size_t)bh * 65536;
  const ushort_t* Kp = kb + (size_t)bh * 65536;
  const ushort_t* VT = vtb + (size_t)bh * 65536;

  const int qrow0 = qt * 128 + wave * 32;

  half8 qf[4];
  #pragma unroll
  for (int ds = 0; ds < 4; ds++)
    qf[ds] = *(const half8*)&Q[(size_t)(qrow0 + l31) * 64 + ds * 16 + hi * 8];

  f32x16 oacc[2];
  oacc[0] = zero16();
  oacc[1] = zero16();
  float m_i = -1e30f, l_i = 0.f;

  const int r7 = l31 & 7;
  int pc[4];
  #pragma unroll
  for (int i = 0; i < 4; i++) pc[i] = (((2 * i + hi) ^ r7) << 3);
  const int ro0 = l31 * 64, ro1 = ro0 + 2048;

  auto stage = [&](int kt, int d) {
    #pragma unroll
    for (int i = 0; i < 2; i++) {
      int g = i * 256 + tid, rw = g >> 3, ch = g & 7;
      int co = ((ch ^ (rw & 7)) << 3);
      int lofs = rw * 64 + (ch << 3);
      async16(&Kp[(size_t)(kt * 64 + rw) * 64 + co], &Ksh[d][lofs]);
      async16(&VT[(size_t)rw * 1024 + kt * 64 + co], &VTs[d][lofs]);
    }
  };

  stage(0, 0);

  for (int kt = 0; kt < 16; kt++) {
    const int cur = kt & 1;
    if (kt < 15) {
      stage(kt + 1, cur ^ 1);
      asm volatile("s_waitcnt vmcnt(4)" ::: "memory");
    } else {
      asm volatile("s_waitcnt vmcnt(0)" ::: "memory");
    }
    __builtin_amdgcn_s_barrier();

    f32x16 sacc0 = zero16(), sacc1 = zero16();
    __builtin_amdgcn_s_setprio(1);
    #pragma unroll
    for (int ds = 0; ds < 4; ds++) {
      half8 k0 = *(const half8*)&Ksh[cur][ro0 + pc[ds]];
      half8 k1 = *(const half8*)&Ksh[cur][ro1 + pc[ds]];
      sacc0 = __builtin_amdgcn_mfma_f32_32x32x16_f16(k0, qf[ds], sacc0, 0, 0, 0);
      sacc1 = __builtin_amdgcn_mfma_f32_32x32x16_f16(k1, qf[ds], sacc1, 0, 0, 0);
    }
    __builtin_amdgcn_s_setprio(0);

    float mx = -1e30f;
    #pragma unroll
    for (int r = 0; r < 16; r++) {
      mx = fmaxf(mx, sacc0[r]);
      mx = fmaxf(mx, sacc1[r]);
    }
    mx = fmaxf(mx, __shfl_xor(mx, 32));
    float mnew = fmaxf(m_i, mx);
    float mL = mnew * LOG2E;
    float alpha = exp2f(fmaf(m_i, LOG2E, -mL));
    float sum = 0.f;
    unsigned pw[16];
    #pragma unroll
    for (int j = 0; j < 8; j++) {
      float p0 = exp2f(fmaf(sacc0[2 * j], LOG2E, -mL));
      float p1 = exp2f(fmaf(sacc0[2 * j + 1], LOG2E, -mL));
      sum += p0 + p1;
      asm("v_cvt_pkrtz_f16_f32 %0, %1, %2" : "=v"(pw[j]) : "v"(p0), "v"(p1));
    }
    #pragma unroll
    for (int j = 0; j < 8; j++) {
      float p0 = exp2f(fmaf(sacc1[2 * j], LOG2E, -mL));
      float p1 = exp2f(fmaf(sacc1[2 * j + 1], LOG2E, -mL));
      sum += p0 + p1;
      asm("v_cvt_pkrtz_f16_f32 %0, %1, %2" : "=v"(pw[8 + j]) : "v"(p0), "v"(p1));
    }
    sum += __shfl_xor(sum, 32);
    l_i = fmaf(l_i, alpha, sum);
    m_i = mnew;
    #pragma unroll
    for (int r = 0; r < 16; r++) {
      oacc[0][r] *= alpha;
      oacc[1][r] *= alpha;
    }

    __builtin_amdgcn_s_setprio(1);
    #pragma unroll
    for (int ks = 0; ks < 4; ks++) {
      const int base = (ks >> 1) * 8 + (ks & 1) * 4;
      uint2v s0 = __builtin_amdgcn_permlane32_swap(pw[base + 0], pw[base + 2], false, false);
      uint2v s1 = __builtin_amdgcn_permlane32_swap(pw[base + 1], pw[base + 3], false, false);
      half8 pfrag = u4h8((uint4v){s0.x, s1.x, s0.y, s1.y});
      half8 vf0 = *(const half8*)&VTs[cur][ro0 + pc[ks]];
      half8 vf1 = *(const half8*)&VTs[cur][ro1 + pc[ks]];
      oacc[0] = __builtin_amdgcn_mfma_f32_32x32x16_f16(vf0, pfrag, oacc[0], 0, 0, 0);
      oacc[1] = __builtin_amdgcn_mfma_f32_32x32x16_f16(vf1, pfrag, oacc[1], 0, 0, 0);
    }
    __builtin_amdgcn_s_setprio(0);

    if (kt < 15) {
      asm volatile("s_waitcnt lgkmcnt(0)" ::: "memory");
      __builtin_amdgcn_s_barrier();
    }
  }

  const int b = bh >> 3, h = bh & 7;
  const int n = qrow0 + l31;
  float rinv = 1.f / l_i;
  #pragma unroll
  for (int dt = 0; dt < 2; dt++) {
    #pragma unroll
    for (int t = 0; t < 4; t++) {
      ushort_t hv[4];
      #pragma unroll
      for (int e = 0; e < 4; e++)
        hv[e] = f2h(oacc[dt][4 * t + e] * rinv);
      size_t idx = (size_t)(b * 1024 + n) * 512 + h * 64 + dt * 32 + t * 8 + hi * 4;
      *(uint2v*)&ob[idx] = (uint2v){(unsigned)hv[0] | ((unsigned)hv[1] << 16),
                                    (unsigned)hv[2] | ((unsigned)hv[3] << 16)};
    }
  }
}

// ---------------- launcher ----------------
extern "C" void kernel_launch(void* const* d_in, const int* in_sizes, int n_in,
                              void* d_out, int out_size, void* d_ws, size_t ws_size,
                              hipStream_t stream) {
  const float* cur = (const float*)d_in[0];   // [8,1024,512] fp32
  const float* hid = (const float*)d_in[1];   // [8,1024,512] fp32
  const float* Wq  = (const float*)d_in[2];   // [512,512]
  const float* Wkv = (const float*)d_in[3];   // [512,1024]
  const float* Wo  = (const float*)d_in[4];   // [512,512]

  ushort_t* ws = (ushort_t*)d_ws;
  ushort_t* C   = ws;                   // 4,194,304  (cur fp16; reused: attn out)
  ushort_t* H   = C + 4194304;          // 4,194,304  (hid fp16)
  ushort_t* ko  = H + 4194304;          // 4,194,304  (k, k-layout)
  ushort_t* vt  = ko + 4194304;         // 4,194,304  (v^T layout)
  ushort_t* qo  = vt + 4194304;         // 4,194,304  (q, q-layout)
  ushort_t* WqT = qo + 4194304;         // 262,144
  ushort_t* WkvT = WqT + 262144;        // 524,288
  ushort_t* WoT = WkvT + 524288;        // 262,144

  // merged ingest: weight transpose (blocks 0..1023) + activation cast (1024..5119)
  prep_all<<<5120, 256, 0, stream>>>(cur, hid, Wq, Wkv, Wo, C, H, WqT, WkvT, WoT);

  // merged kv + q projections: 768 blocks (128x128 tiles), XCD-contiguous work
  gemm_qkv<<<768, 256, 0, stream>>>(H, WkvT, ko, vt, C, WqT, qo);

  // attention: 512 blocks (head-major XCD grouping), 128 q-rows/block; out -> C
  flash_attn<<<512, 256, 0, stream>>>(qo, ko, vt, C);

  // output projection: 512 blocks -> fp32 d_out
  gemm_o<<<512, 256, 0, stream>>>(C, WoT, (float*)d_out);
}